// Round 10
// baseline (487.245 us; speedup 1.0000x reference)
//
#include <hip/hip_runtime.h>
#include <hip/hip_bf16.h>
#include <math.h>

#define BB 32
#define SS 4096
#define DMEM 512
#define DATT 512

typedef short short8 __attribute__((ext_vector_type(8)));
typedef float floatx4 __attribute__((ext_vector_type(4)));

__device__ inline short f2bf(float x) {
    unsigned u = __float_as_uint(x);
    unsigned r = (u + 0x7fffu + ((u >> 16) & 1u)) >> 16;
    return (short)(r & 0xffffu);
}

// tanh via exp + hardware rcp (v_rcp_f32, ~1ulp).
__device__ inline float fast_tanh(float x) {
    float e = __expf(2.0f * x);
    float r = __builtin_amdgcn_rcpf(e + 1.0f);
    return __builtin_fmaf(-2.0f, r, 1.0f);
}

// async 16B global->LDS DMA; lds base wave-uniform, HW adds lane*16.
__device__ inline void gld_lds16(const void* g, void* l) {
    __builtin_amdgcn_global_load_lds(
        (const __attribute__((address_space(1))) unsigned int*)g,
        (__attribute__((address_space(3))) unsigned int*)l, 16, 0, 0);
}

// ---------------- prep kernels (unchanged, proven) ----------------

__global__ void prep_wt_kernel(const float* __restrict__ Wm, short* __restrict__ Wt) {
    const int n0 = blockIdx.x * 32;
    const int k0 = blockIdx.y * 32;
    const int t = threadIdx.x;
    const int r = t >> 5, c = t & 31;
    __shared__ float lds[32 * 33];
#pragma unroll
    for (int j = 0; j < 4; ++j) {
        int kk = r + j * 8;
        lds[kk * 33 + c] = Wm[(size_t)(k0 + kk) * 512 + n0 + c];
    }
    __syncthreads();
#pragma unroll
    for (int j = 0; j < 4; ++j) {
        int nn = r + j * 8;
        Wt[(size_t)(n0 + nn) * 512 + k0 + c] = f2bf(lds[c * 33 + nn]);
    }
}

__global__ void prep_h_kernel(const float* __restrict__ hidden, const float* __restrict__ Wh,
                              float* __restrict__ h) {
    const int b = blockIdx.x;
    const int n = blockIdx.y * 256 + threadIdx.x;
    const int kc = blockIdx.z;
    float acc = 0.f;
#pragma unroll 8
    for (int k = kc * 128; k < kc * 128 + 128; ++k)
        acc += hidden[b * 512 + k] * Wh[(size_t)k * 512 + n];
    atomicAdd(&h[b * 512 + n], acc);
}

// ---------------- fused score + partial softmax + context (split-S flash) ----------
// R9 post-mortem: counted-vmcnt 2-phase loop = -15% (170us) but per-kt is still
// ~5500 cyc vs ~1900 floor (A-HBM 1600 / LDS 1900 / MFMA 320). The gap matches
// m141's measured anti-pattern: I had FIVE sched_barrier(0) walls per kt, which
// forbid the compiler's fine-grained ds_read||VALU||MFMA interleave (m141: -42%).
// R10: identical schedule, ZERO sched_barriers. Ordering is preserved by the
// "memory" clobbers on the waitcnt asm (no memory op crosses them) and by the
// s_barrier sitting between those asm walls. vmcnt counts unchanged (FIFO B,B,A
// at end-wait -> vmcnt(1) retires B(kt+1), keeps A(kt+2) in flight).
// Per kt: issue B-DMA(kt+1) | ds_read frags(kt) | ds_write A(kt+1) (compiler-
// counted wait on load issued a full kt ago) | issue A(kt+2) | 16 MFMA |
// vmcnt(1) | lgkmcnt(0) | ONE s_barrier. Never drain vmcnt except kt=14.
// 1024 thr = 16 waves (2m x 8n); acc[4][4] = 64 AGPR + ~64 arch -> 4 waves/SIMD.

__global__ __launch_bounds__(1024, 4)
void fused_kernel(const float* __restrict__ memory,
                  const float* __restrict__ coverage,
                  const unsigned char* __restrict__ pad,
                  const short* __restrict__ Wt,
                  const float* __restrict__ h,
                  const float* __restrict__ Wc,
                  const float* __restrict__ v,
                  float* __restrict__ pOut,     // = attn output buffer (unnormalized p)
                  float* __restrict__ mWS,
                  float* __restrict__ lWS,
                  float* __restrict__ ctxPart) {
    const int blk = blockIdx.x;
    const int b = blk >> 5;
    const int st = blk & 31;
    const int s0 = st * 128;

    const int tid = threadIdx.x;
    const int lane = tid & 63;
    const int wave = tid >> 6;     // 0..15
    const int wm = wave & 1;       // 2-way m split (64 rows each)
    const int wn = wave >> 1;      // 8-way n split (64 cols each)
    const int col = lane & 15;
    const int q = lane >> 4;

    // LDS map (~85.5 KB -> 1 block/CU, 16 waves):
    //   [0,32768)      bufB0   512 rows x 64B bf16 (BK=32)
    //   [32768,65536)  bufB1
    //   [65536,73728)  bufA0   128 rows x 64B bf16 (XOR layout)
    //   [73728,81920)  bufA1
    //   [81920,...)    covS 512 | sred[8][128] 4096 | scoreS 512 | pS 512 | mlS 8
    __shared__ __align__(16) char smem[87560];
    char* bufB0 = smem;
    char* bufB1 = smem + 32768;
    char* bufA0 = smem + 65536;
    char* bufA1 = smem + 73728;
    float* covS   = (float*)(smem + 81920);
    float* sred   = (float*)(smem + 82432);   // [8][128]
    float* scoreS = (float*)(smem + 86528);
    float* pS     = (float*)(smem + 87040);
    float* mlS    = (float*)(smem + 87552);
    float4* red4  = (float4*)smem;            // PV reduce [8][128] f4 = 16 KB, aliases bufB0

    if (tid < 128) covS[tid] = coverage[(size_t)b * SS + s0 + tid];

    const float4* gA4 = (const float4*)(memory + ((size_t)b * SS + s0) * 512);  // row=128 f4
    const char* gB = (const char*)Wt;         // row pitch 1024B (K=512), 512 rows

    // A staging (BK=32): 128 rows x 8 slots of 16B fp32 = 1024 slots = 1/thread.
    const int arow = tid >> 3, al8 = tid & 7;
    const int aoff = arow * 64 + (((al8 >> 1) ^ ((arow >> 1) & 3)) << 4) + ((al8 & 1) << 3);

    float4 apfA;

    floatx4 acc[4][4];
#pragma unroll
    for (int mi = 0; mi < 4; ++mi)
#pragma unroll
        for (int ni = 0; ni < 4; ++ni)
            acc[mi][ni] = (floatx4){0.f, 0.f, 0.f, 0.f};

    // ---- prologue: A(0) load -> B(0) DMA -> write A(0) -> A(1) load -> counted wait ----
    apfA = gA4[(size_t)arow * 128 + al8];                  // A(0)   [vm, oldest]
#pragma unroll
    for (int it = 0; it < 2; ++it) {                       // B(0)   [vm x2]
        int ci = it * 1024 + tid;
        int row = ci >> 2;
        int gch = (ci & 3) ^ ((row >> 1) & 3);
        gld_lds16(gB + (size_t)row * 1024 + gch * 16,
                  bufB0 + it * 16384 + wave * 1024);
    }
    {
        // ds_write A(0): compiler waits apfA with counted vmcnt (allows the 2 B-DMAs)
        union { __hip_bfloat162 h2; unsigned u; } p0, p1;
        p0.h2 = __float22bfloat162_rn(make_float2(apfA.x, apfA.y));
        p1.h2 = __float22bfloat162_rn(make_float2(apfA.z, apfA.w));
        uint2 w; w.x = p0.u; w.y = p1.u;
        *(uint2*)(bufA0 + aoff) = w;
    }
    apfA = gA4[(size_t)arow * 128 + 8 + al8];              // A(1) in flight
    asm volatile("s_waitcnt vmcnt(1)" ::: "memory");       // B(0) done; A(1) flying
    asm volatile("s_waitcnt lgkmcnt(0)" ::: "memory");
    __builtin_amdgcn_s_barrier();                          // tile 0 ready

#pragma unroll
    for (int kt = 0; kt < 16; ++kt) {
        // ---- issue B-DMA(kt+1) into the other buffer ----
        if (kt < 15) {
            char* ldsB = ((kt + 1) & 1) ? bufB1 : bufB0;   // static under unroll
#pragma unroll
            for (int it = 0; it < 2; ++it) {
                int ci = it * 1024 + tid;
                int row = ci >> 2;
                int gch = (ci & 3) ^ ((row >> 1) & 3);
                gld_lds16(gB + (size_t)row * 1024 + (kt + 1) * 64 + gch * 16,
                          ldsB + it * 16384 + wave * 1024);
            }
        }

        // ---- ds_read frags(kt) ----
        const char* abase = (kt & 1) ? bufA1 : bufA0;
        const char* bbase = (kt & 1) ? bufB1 : bufB0;
        short8 af[4], bf[4];
#pragma unroll
        for (int mi = 0; mi < 4; ++mi) {
            int row = wm * 64 + mi * 16 + col;
            af[mi] = *(const short8*)(abase + row * 64 + ((q ^ ((row >> 1) & 3)) << 4));
        }
#pragma unroll
        for (int ni = 0; ni < 4; ++ni) {
            int row = wn * 64 + ni * 16 + col;
            bf[ni] = *(const short8*)(bbase + row * 64 + ((q ^ ((row >> 1) & 3)) << 4));
        }

        // ---- ds_write A(kt+1) (counted wait: apfA issued a full kt ago), reissue A ----
        if (kt < 15) {
            union { __hip_bfloat162 h2; unsigned u; } p0, p1;
            p0.h2 = __float22bfloat162_rn(make_float2(apfA.x, apfA.y));
            p1.h2 = __float22bfloat162_rn(make_float2(apfA.z, apfA.w));
            uint2 w; w.x = p0.u; w.y = p1.u;
            char* dst = ((kt + 1) & 1) ? bufA1 : bufA0;
            *(uint2*)(dst + aoff) = w;
            if (kt < 14)
                apfA = gA4[(size_t)arow * 128 + (kt + 2) * 8 + al8];
        }

        // ---- 16 MFMA (covers B-DMA + A-load latency) ----
#pragma unroll
        for (int mi = 0; mi < 4; ++mi)
#pragma unroll
            for (int ni = 0; ni < 4; ++ni)
                acc[mi][ni] = __builtin_amdgcn_mfma_f32_16x16x32_bf16(af[mi], bf[ni], acc[mi][ni], 0, 0, 0);

        // ---- one counted barrier per kt; vmcnt never drained while A in flight ----
        if (kt < 15) {
            if (kt < 14) {
                asm volatile("s_waitcnt vmcnt(1)" ::: "memory");  // B(kt+1) done, A(kt+2) flying
            } else {
                asm volatile("s_waitcnt vmcnt(0)" ::: "memory");  // kt=14: nothing left to fly
            }
            asm volatile("s_waitcnt lgkmcnt(0)" ::: "memory");
            __builtin_amdgcn_s_barrier();
        }
    }

    __syncthreads();   // single full drain before epilogue

    // ---- epilogue: tile scores = sum_n tanh(acc + h + cov*Wc) * v ----
    float hv[4], wcv[4], vv[4];
#pragma unroll
    for (int ni = 0; ni < 4; ++ni) {
        int n = wn * 64 + ni * 16 + col;
        hv[ni] = h[b * 512 + n];
        wcv[ni] = Wc[n];
        vv[ni] = v[n];
    }
    float rowAcc[4][4];
#pragma unroll
    for (int mi = 0; mi < 4; ++mi)
#pragma unroll
        for (int r = 0; r < 4; ++r)
            rowAcc[mi][r] = 0.f;
#pragma unroll
    for (int mi = 0; mi < 4; ++mi) {
#pragma unroll
        for (int r = 0; r < 4; ++r) {
            float cv = covS[wm * 64 + mi * 16 + q * 4 + r];
#pragma unroll
            for (int ni = 0; ni < 4; ++ni) {
                float val = acc[mi][ni][r] + hv[ni] + cv * wcv[ni];
                rowAcc[mi][r] += fast_tanh(val) * vv[ni];
            }
        }
    }
#pragma unroll
    for (int off = 1; off < 16; off <<= 1)
#pragma unroll
        for (int mi = 0; mi < 4; ++mi)
#pragma unroll
            for (int r = 0; r < 4; ++r)
                rowAcc[mi][r] += __shfl_xor(rowAcc[mi][r], off, 64);

    if (col == 0) {
#pragma unroll
        for (int mi = 0; mi < 4; ++mi)
#pragma unroll
            for (int r = 0; r < 4; ++r)
                sred[wn * 128 + wm * 64 + mi * 16 + q * 4 + r] = rowAcc[mi][r];
    }
    __syncthreads();

    // ---- tile softmax (m, p, l) ----
    if (tid < 128) {
        float sc = 0.f;
#pragma unroll
        for (int w = 0; w < 8; ++w) sc += sred[w * 128 + tid];
        if (pad[(size_t)b * SS + s0 + tid]) sc = -INFINITY;
        scoreS[tid] = sc;
    }
    __syncthreads();
    if (tid < 64) {
        float mx = fmaxf(scoreS[tid], scoreS[tid + 64]);
#pragma unroll
        for (int off = 32; off >= 1; off >>= 1) mx = fmaxf(mx, __shfl_xor(mx, off, 64));
        if (tid == 0) mlS[0] = mx;
    }
    __syncthreads();
    const float mtile = mlS[0];
    if (tid < 128) pS[tid] = __expf(scoreS[tid] - mtile);
    __syncthreads();
    if (tid < 64) {
        float sm = pS[tid] + pS[tid + 64];
#pragma unroll
        for (int off = 32; off >= 1; off >>= 1) sm += __shfl_xor(sm, off, 64);
        if (tid == 0) mlS[1] = sm;
    }
    __syncthreads();

    if (tid < 128) pOut[(size_t)b * SS + s0 + tid] = pS[tid];
    if (tid == 0) {
        mWS[b * 32 + st] = mtile;
        lWS[b * 32 + st] = mlS[1];
    }

    // ---- PV: ctxPart[d] = sum_s p[s] * memory_fp32[s,d]  (tile is cache-hot) ----
    const int sg = tid >> 7;       // 8 groups of 16 s-rows
    const int dc = tid & 127;      // float4 column
    const float4* m4 = (const float4*)(memory + ((size_t)b * SS + s0) * 512);
    float4 a4 = {0.f, 0.f, 0.f, 0.f};
#pragma unroll 8
    for (int i = 0; i < 16; ++i) {
        int s = sg * 16 + i;
        float w = pS[s];
        float4 f = m4[(size_t)s * 128 + dc];
        a4.x += w * f.x; a4.y += w * f.y; a4.z += w * f.z; a4.w += w * f.w;
    }
    red4[sg * 128 + dc] = a4;      // [8][128] f4, aliases bufB0 (GEMM done)
    __syncthreads();
    if (tid < 128) {
        float4 o = {0.f, 0.f, 0.f, 0.f};
#pragma unroll
        for (int g2 = 0; g2 < 8; ++g2) {
            float4 r = red4[g2 * 128 + tid];
            o.x += r.x; o.y += r.y; o.z += r.z; o.w += r.w;
        }
        ((float4*)(ctxPart + ((size_t)(b * 32 + st)) * 512))[tid] = o;
    }
}

// ---------------- combine: cross-tile softmax merge -> attn (in place), ctx --------
__global__ __launch_bounds__(512)
void combine_kernel(const float* __restrict__ mWS,
                    const float* __restrict__ lWS,
                    const float* __restrict__ ctxPart,
                    float* __restrict__ ctx,
                    float* __restrict__ attn) {
    const int b = blockIdx.x;
    const int tid = threadIdx.x;   // 512
    __shared__ float scaleS[32];
    __shared__ float gS[2];

    if (tid < 64) {
        float mv = (tid < 32) ? mWS[b * 32 + tid] : -INFINITY;
#pragma unroll
        for (int off = 32; off >= 1; off >>= 1) mv = fmaxf(mv, __shfl_xor(mv, off, 64));
        if (tid == 0) gS[0] = mv;
    }
    __syncthreads();
    const float gmax = gS[0];
    if (tid < 64) {
        float sc = 0.f, lv = 0.f;
        if (tid < 32) {
            sc = __expf(mWS[b * 32 + tid] - gmax);
            scaleS[tid] = sc;
            lv = lWS[b * 32 + tid] * sc;
        }
#pragma unroll
        for (int off = 32; off >= 1; off >>= 1) lv += __shfl_xor(lv, off, 64);
        if (tid == 0) gS[1] = lv;
    }
    __syncthreads();
    const float inv = 1.0f / gS[1];

    // ctx[b, d] = sum_st ctxPart[st, d] * scale[st] * inv   (no atomics)
    float facc = 0.f;
#pragma unroll 8
    for (int st = 0; st < 32; ++st)
        facc += ctxPart[((size_t)(b * 32 + st)) * 512 + tid] * scaleS[st];
    ctx[b * 512 + tid] = facc * inv;

    // attn[b, s] holds unnormalized p -> rescale in place
#pragma unroll
    for (int j = 0; j < 8; ++j) {
        size_t idx = (size_t)b * SS + j * 512 + tid;
        attn[idx] = attn[idx] * scaleS[(j * 512 + tid) >> 7] * inv;
    }
}

// ---------------- launch ----------------
extern "C" void kernel_launch(void* const* d_in, const int* in_sizes, int n_in,
                              void* d_out, int out_size, void* d_ws, size_t ws_size,
                              hipStream_t stream) {
    (void)in_sizes; (void)n_in; (void)out_size; (void)ws_size;
    const float* hidden   = (const float*)d_in[0];
    const float* memory   = (const float*)d_in[1];
    const unsigned char* mem_pad = (const unsigned char*)d_in[2];
    const float* coverage = (const float*)d_in[3];
    const float* Wh       = (const float*)d_in[4];
    const float* Wm       = (const float*)d_in[5];
    const float* Wc       = (const float*)d_in[6];
    const float* v        = (const float*)d_in[7];

    char* ws = (char*)d_ws;
    short* Wt      = (short*)ws;                       // 512 KB
    float* h       = (float*)(ws + 512 * 1024);        // 64 KB
    float* mWS     = (float*)(ws + 576 * 1024);        // 4 KB (32 x 32)
    float* lWS     = (float*)(ws + 580 * 1024);        // 4 KB
    float* ctxPart = (float*)(ws + 584 * 1024);        // 2 MB (32 x 32 x 512)
    // total ws use: 2.57 MB  (<= 2.625 MB proven envelope)

    float* ctx  = (float*)d_out;
    float* attn = (float*)d_out + BB * 512;            // doubles as p buffer

    hipMemsetAsync(h, 0, BB * 512 * sizeof(float), stream);
    prep_wt_kernel<<<dim3(16, 16), dim3(256), 0, stream>>>(Wm, Wt);
    prep_h_kernel<<<dim3(32, 2, 4), dim3(256), 0, stream>>>(hidden, Wh, h);
    fused_kernel<<<dim3(BB * 32), dim3(1024), 0, stream>>>(
        memory, coverage, mem_pad, Wt, h, Wc, v, attn, mWS, lWS, ctxPart);
    combine_kernel<<<dim3(BB), dim3(512), 0, stream>>>(mWS, lWS, ctxPart, ctx, attn);
}

// Round 11
// 453.766 us; speedup vs baseline: 1.0738x; 1.0738x over previous
//
#include <hip/hip_runtime.h>
#include <hip/hip_bf16.h>
#include <math.h>

#define BB 32
#define SS 4096
#define DMEM 512
#define DATT 512

typedef short short8 __attribute__((ext_vector_type(8)));
typedef float floatx4 __attribute__((ext_vector_type(4)));

__device__ inline short f2bf(float x) {
    unsigned u = __float_as_uint(x);
    unsigned r = (u + 0x7fffu + ((u >> 16) & 1u)) >> 16;
    return (short)(r & 0xffffu);
}

// tanh via exp + hardware rcp (v_rcp_f32, ~1ulp).
__device__ inline float fast_tanh(float x) {
    float e = __expf(2.0f * x);
    float r = __builtin_amdgcn_rcpf(e + 1.0f);
    return __builtin_fmaf(-2.0f, r, 1.0f);
}

// async 16B global->LDS DMA; lds base wave-uniform, HW adds lane*16.
__device__ inline void gld_lds16(const void* g, void* l) {
    __builtin_amdgcn_global_load_lds(
        (const __attribute__((address_space(1))) unsigned int*)g,
        (__attribute__((address_space(3))) unsigned int*)l, 16, 0, 0);
}

// ---------------- prep kernels (unchanged, proven) ----------------

__global__ void prep_wt_kernel(const float* __restrict__ Wm, short* __restrict__ Wt) {
    const int n0 = blockIdx.x * 32;
    const int k0 = blockIdx.y * 32;
    const int t = threadIdx.x;
    const int r = t >> 5, c = t & 31;
    __shared__ float lds[32 * 33];
#pragma unroll
    for (int j = 0; j < 4; ++j) {
        int kk = r + j * 8;
        lds[kk * 33 + c] = Wm[(size_t)(k0 + kk) * 512 + n0 + c];
    }
    __syncthreads();
#pragma unroll
    for (int j = 0; j < 4; ++j) {
        int nn = r + j * 8;
        Wt[(size_t)(n0 + nn) * 512 + k0 + c] = f2bf(lds[c * 33 + nn]);
    }
}

__global__ void prep_h_kernel(const float* __restrict__ hidden, const float* __restrict__ Wh,
                              float* __restrict__ h) {
    const int b = blockIdx.x;
    const int n = blockIdx.y * 256 + threadIdx.x;
    const int kc = blockIdx.z;
    float acc = 0.f;
#pragma unroll 8
    for (int k = kc * 128; k < kc * 128 + 128; ++k)
        acc += hidden[b * 512 + k] * Wh[(size_t)k * 512 + n];
    atomicAdd(&h[b * 512 + n], acc);
}

// ---------------- fused score + partial softmax + context (split-S flash) ----------
// R9 (5 pins/kt) = 170us. R10 (0 pins) = 203us + 113MB scratch WRITE: at the 128-reg
// unified cap, unpinned MFMAs sank past the barrier cluster ("memory" clobber does
// not order register-only ops, rule 18) -> af/bf liveness across iterations -> spill.
// R11: MINIMAL pin set, 2 per kt:
//   pin#1 after B-DMA issue  -> vm-queue FIFO guaranteed B,B,A so vmcnt(1) at the
//        barrier retires B(kt+1) and keeps A(kt+2) flying (correctness of count);
//   pin#2 before the waitcnt cluster -> bounds MFMA sinking (the R10 spill fix).
// Everything between is free for the compiler to interleave (m141 lesson).
// Schedule per kt (unchanged from R9): issue B-DMA(kt+1) | ds_read frags(kt) |
// ds_write A(kt+1) (compiler-counted wait on a load issued a full kt ago) |
// issue A(kt+2) | 16 MFMA | vmcnt(1) lgkmcnt(0) | ONE s_barrier.
// 1024 thr = 16 waves (2m x 8n); acc[4][4] = 64 AGPR + 64 arch -> 4 waves/SIMD.

__global__ __launch_bounds__(1024, 4)
void fused_kernel(const float* __restrict__ memory,
                  const float* __restrict__ coverage,
                  const unsigned char* __restrict__ pad,
                  const short* __restrict__ Wt,
                  const float* __restrict__ h,
                  const float* __restrict__ Wc,
                  const float* __restrict__ v,
                  float* __restrict__ pOut,     // = attn output buffer (unnormalized p)
                  float* __restrict__ mWS,
                  float* __restrict__ lWS,
                  float* __restrict__ ctxPart) {
    const int blk = blockIdx.x;
    const int b = blk >> 5;
    const int st = blk & 31;
    const int s0 = st * 128;

    const int tid = threadIdx.x;
    const int lane = tid & 63;
    const int wave = tid >> 6;     // 0..15
    const int wm = wave & 1;       // 2-way m split (64 rows each)
    const int wn = wave >> 1;      // 8-way n split (64 cols each)
    const int col = lane & 15;
    const int q = lane >> 4;

    // LDS map (~85.5 KB -> 1 block/CU, 16 waves):
    //   [0,32768)      bufB0   512 rows x 64B bf16 (BK=32)
    //   [32768,65536)  bufB1
    //   [65536,73728)  bufA0   128 rows x 64B bf16 (XOR layout)
    //   [73728,81920)  bufA1
    //   [81920,...)    covS 512 | sred[8][128] 4096 | scoreS 512 | pS 512 | mlS 8
    __shared__ __align__(16) char smem[87560];
    char* bufB0 = smem;
    char* bufB1 = smem + 32768;
    char* bufA0 = smem + 65536;
    char* bufA1 = smem + 73728;
    float* covS   = (float*)(smem + 81920);
    float* sred   = (float*)(smem + 82432);   // [8][128]
    float* scoreS = (float*)(smem + 86528);
    float* pS     = (float*)(smem + 87040);
    float* mlS    = (float*)(smem + 87552);
    float4* red4  = (float4*)smem;            // PV reduce [8][128] f4 = 16 KB, aliases bufB0

    if (tid < 128) covS[tid] = coverage[(size_t)b * SS + s0 + tid];

    const float4* gA4 = (const float4*)(memory + ((size_t)b * SS + s0) * 512);  // row=128 f4
    const char* gB = (const char*)Wt;         // row pitch 1024B (K=512), 512 rows

    // A staging (BK=32): 128 rows x 8 slots of 16B fp32 = 1024 slots = 1/thread.
    const int arow = tid >> 3, al8 = tid & 7;
    const int aoff = arow * 64 + (((al8 >> 1) ^ ((arow >> 1) & 3)) << 4) + ((al8 & 1) << 3);

    float4 apfA;

    floatx4 acc[4][4];
#pragma unroll
    for (int mi = 0; mi < 4; ++mi)
#pragma unroll
        for (int ni = 0; ni < 4; ++ni)
            acc[mi][ni] = (floatx4){0.f, 0.f, 0.f, 0.f};

    // ---- prologue: A(0) load -> B(0) DMA -> write A(0) -> A(1) load -> counted wait ----
    apfA = gA4[(size_t)arow * 128 + al8];                  // A(0)
#pragma unroll
    for (int it = 0; it < 2; ++it) {                       // B(0) DMA x2
        int ci = it * 1024 + tid;
        int row = ci >> 2;
        int gch = (ci & 3) ^ ((row >> 1) & 3);
        gld_lds16(gB + (size_t)row * 1024 + gch * 16,
                  bufB0 + it * 16384 + wave * 1024);
    }
    __builtin_amdgcn_sched_barrier(0);   // pin: B(0) DMAs older than A(1) load
    {
        // ds_write A(0): compiler waits apfA with counted vmcnt (allows the 2 B-DMAs)
        union { __hip_bfloat162 h2; unsigned u; } p0, p1;
        p0.h2 = __float22bfloat162_rn(make_float2(apfA.x, apfA.y));
        p1.h2 = __float22bfloat162_rn(make_float2(apfA.z, apfA.w));
        uint2 w; w.x = p0.u; w.y = p1.u;
        *(uint2*)(bufA0 + aoff) = w;
    }
    apfA = gA4[(size_t)arow * 128 + 8 + al8];              // A(1) in flight
    __builtin_amdgcn_sched_barrier(0);   // pin: all above emitted before waits
    asm volatile("s_waitcnt vmcnt(1)" ::: "memory");       // B(0) done; A(1) flying
    asm volatile("s_waitcnt lgkmcnt(0)" ::: "memory");
    __builtin_amdgcn_s_barrier();                          // tile 0 ready

#pragma unroll
    for (int kt = 0; kt < 16; ++kt) {
        // ---- issue B-DMA(kt+1) into the other buffer ----
        if (kt < 15) {
            char* ldsB = ((kt + 1) & 1) ? bufB1 : bufB0;   // static under unroll
#pragma unroll
            for (int it = 0; it < 2; ++it) {
                int ci = it * 1024 + tid;
                int row = ci >> 2;
                int gch = (ci & 3) ^ ((row >> 1) & 3);
                gld_lds16(gB + (size_t)row * 1024 + (kt + 1) * 64 + gch * 16,
                          ldsB + it * 16384 + wave * 1024);
            }
            // pin#1: keep the 2 B-DMAs oldest in the vm queue (vmcnt count depends on it)
            __builtin_amdgcn_sched_barrier(0);
        }

        // ---- ds_read frags(kt) ----
        const char* abase = (kt & 1) ? bufA1 : bufA0;
        const char* bbase = (kt & 1) ? bufB1 : bufB0;
        short8 af[4], bf[4];
#pragma unroll
        for (int mi = 0; mi < 4; ++mi) {
            int row = wm * 64 + mi * 16 + col;
            af[mi] = *(const short8*)(abase + row * 64 + ((q ^ ((row >> 1) & 3)) << 4));
        }
#pragma unroll
        for (int ni = 0; ni < 4; ++ni) {
            int row = wn * 64 + ni * 16 + col;
            bf[ni] = *(const short8*)(bbase + row * 64 + ((q ^ ((row >> 1) & 3)) << 4));
        }

        // ---- ds_write A(kt+1) (counted wait: apfA issued a full kt ago), reissue A ----
        if (kt < 15) {
            union { __hip_bfloat162 h2; unsigned u; } p0, p1;
            p0.h2 = __float22bfloat162_rn(make_float2(apfA.x, apfA.y));
            p1.h2 = __float22bfloat162_rn(make_float2(apfA.z, apfA.w));
            uint2 w; w.x = p0.u; w.y = p1.u;
            char* dst = ((kt + 1) & 1) ? bufA1 : bufA0;
            *(uint2*)(dst + aoff) = w;
            if (kt < 14)
                apfA = gA4[(size_t)arow * 128 + (kt + 2) * 8 + al8];
        }

        // ---- 16 MFMA (covers B-DMA + A-load latency) ----
#pragma unroll
        for (int mi = 0; mi < 4; ++mi)
#pragma unroll
            for (int ni = 0; ni < 4; ++ni)
                acc[mi][ni] = __builtin_amdgcn_mfma_f32_16x16x32_bf16(af[mi], bf[ni], acc[mi][ni], 0, 0, 0);

        // ---- one counted barrier per kt; vmcnt never drained while A in flight ----
        if (kt < 15) {
            // pin#2: bound MFMA sinking (R10 spill fix) -- everything above emits first
            __builtin_amdgcn_sched_barrier(0);
            if (kt < 14) {
                asm volatile("s_waitcnt vmcnt(1)" ::: "memory");  // B(kt+1) done, A(kt+2) flying
            } else {
                asm volatile("s_waitcnt vmcnt(0)" ::: "memory");  // kt=14: nothing left to fly
            }
            asm volatile("s_waitcnt lgkmcnt(0)" ::: "memory");
            __builtin_amdgcn_s_barrier();
        }
    }

    __syncthreads();   // single full drain before epilogue

    // ---- epilogue: tile scores = sum_n tanh(acc + h + cov*Wc) * v ----
    float hv[4], wcv[4], vv[4];
#pragma unroll
    for (int ni = 0; ni < 4; ++ni) {
        int n = wn * 64 + ni * 16 + col;
        hv[ni] = h[b * 512 + n];
        wcv[ni] = Wc[n];
        vv[ni] = v[n];
    }
    float rowAcc[4][4];
#pragma unroll
    for (int mi = 0; mi < 4; ++mi)
#pragma unroll
        for (int r = 0; r < 4; ++r)
            rowAcc[mi][r] = 0.f;
#pragma unroll
    for (int mi = 0; mi < 4; ++mi) {
#pragma unroll
        for (int r = 0; r < 4; ++r) {
            float cv = covS[wm * 64 + mi * 16 + q * 4 + r];
#pragma unroll
            for (int ni = 0; ni < 4; ++ni) {
                float val = acc[mi][ni][r] + hv[ni] + cv * wcv[ni];
                rowAcc[mi][r] += fast_tanh(val) * vv[ni];
            }
        }
    }
#pragma unroll
    for (int off = 1; off < 16; off <<= 1)
#pragma unroll
        for (int mi = 0; mi < 4; ++mi)
#pragma unroll
            for (int r = 0; r < 4; ++r)
                rowAcc[mi][r] += __shfl_xor(rowAcc[mi][r], off, 64);

    if (col == 0) {
#pragma unroll
        for (int mi = 0; mi < 4; ++mi)
#pragma unroll
            for (int r = 0; r < 4; ++r)
                sred[wn * 128 + wm * 64 + mi * 16 + q * 4 + r] = rowAcc[mi][r];
    }
    __syncthreads();

    // ---- tile softmax (m, p, l) ----
    if (tid < 128) {
        float sc = 0.f;
#pragma unroll
        for (int w = 0; w < 8; ++w) sc += sred[w * 128 + tid];
        if (pad[(size_t)b * SS + s0 + tid]) sc = -INFINITY;
        scoreS[tid] = sc;
    }
    __syncthreads();
    if (tid < 64) {
        float mx = fmaxf(scoreS[tid], scoreS[tid + 64]);
#pragma unroll
        for (int off = 32; off >= 1; off >>= 1) mx = fmaxf(mx, __shfl_xor(mx, off, 64));
        if (tid == 0) mlS[0] = mx;
    }
    __syncthreads();
    const float mtile = mlS[0];
    if (tid < 128) pS[tid] = __expf(scoreS[tid] - mtile);
    __syncthreads();
    if (tid < 64) {
        float sm = pS[tid] + pS[tid + 64];
#pragma unroll
        for (int off = 32; off >= 1; off >>= 1) sm += __shfl_xor(sm, off, 64);
        if (tid == 0) mlS[1] = sm;
    }
    __syncthreads();

    if (tid < 128) pOut[(size_t)b * SS + s0 + tid] = pS[tid];
    if (tid == 0) {
        mWS[b * 32 + st] = mtile;
        lWS[b * 32 + st] = mlS[1];
    }

    // ---- PV: ctxPart[d] = sum_s p[s] * memory_fp32[s,d]  (tile is cache-hot) ----
    const int sg = tid >> 7;       // 8 groups of 16 s-rows
    const int dc = tid & 127;      // float4 column
    const float4* m4 = (const float4*)(memory + ((size_t)b * SS + s0) * 512);
    float4 a4 = {0.f, 0.f, 0.f, 0.f};
#pragma unroll 8
    for (int i = 0; i < 16; ++i) {
        int s = sg * 16 + i;
        float w = pS[s];
        float4 f = m4[(size_t)s * 128 + dc];
        a4.x += w * f.x; a4.y += w * f.y; a4.z += w * f.z; a4.w += w * f.w;
    }
    red4[sg * 128 + dc] = a4;      // [8][128] f4, aliases bufB0 (GEMM done)
    __syncthreads();
    if (tid < 128) {
        float4 o = {0.f, 0.f, 0.f, 0.f};
#pragma unroll
        for (int g2 = 0; g2 < 8; ++g2) {
            float4 r = red4[g2 * 128 + tid];
            o.x += r.x; o.y += r.y; o.z += r.z; o.w += r.w;
        }
        ((float4*)(ctxPart + ((size_t)(b * 32 + st)) * 512))[tid] = o;
    }
}

// ---------------- combine: cross-tile softmax merge -> attn (in place), ctx --------
__global__ __launch_bounds__(512)
void combine_kernel(const float* __restrict__ mWS,
                    const float* __restrict__ lWS,
                    const float* __restrict__ ctxPart,
                    float* __restrict__ ctx,
                    float* __restrict__ attn) {
    const int b = blockIdx.x;
    const int tid = threadIdx.x;   // 512
    __shared__ float scaleS[32];
    __shared__ float gS[2];

    if (tid < 64) {
        float mv = (tid < 32) ? mWS[b * 32 + tid] : -INFINITY;
#pragma unroll
        for (int off = 32; off >= 1; off >>= 1) mv = fmaxf(mv, __shfl_xor(mv, off, 64));
        if (tid == 0) gS[0] = mv;
    }
    __syncthreads();
    const float gmax = gS[0];
    if (tid < 64) {
        float sc = 0.f, lv = 0.f;
        if (tid < 32) {
            sc = __expf(mWS[b * 32 + tid] - gmax);
            scaleS[tid] = sc;
            lv = lWS[b * 32 + tid] * sc;
        }
#pragma unroll
        for (int off = 32; off >= 1; off >>= 1) lv += __shfl_xor(lv, off, 64);
        if (tid == 0) gS[1] = lv;
    }
    __syncthreads();
    const float inv = 1.0f / gS[1];

    // ctx[b, d] = sum_st ctxPart[st, d] * scale[st] * inv   (no atomics)
    float facc = 0.f;
#pragma unroll 8
    for (int st = 0; st < 32; ++st)
        facc += ctxPart[((size_t)(b * 32 + st)) * 512 + tid] * scaleS[st];
    ctx[b * 512 + tid] = facc * inv;

    // attn[b, s] holds unnormalized p -> rescale in place
#pragma unroll
    for (int j = 0; j < 8; ++j) {
        size_t idx = (size_t)b * SS + j * 512 + tid;
        attn[idx] = attn[idx] * scaleS[(j * 512 + tid) >> 7] * inv;
    }
}

// ---------------- launch ----------------
extern "C" void kernel_launch(void* const* d_in, const int* in_sizes, int n_in,
                              void* d_out, int out_size, void* d_ws, size_t ws_size,
                              hipStream_t stream) {
    (void)in_sizes; (void)n_in; (void)out_size; (void)ws_size;
    const float* hidden   = (const float*)d_in[0];
    const float* memory   = (const float*)d_in[1];
    const unsigned char* mem_pad = (const unsigned char*)d_in[2];
    const float* coverage = (const float*)d_in[3];
    const float* Wh       = (const float*)d_in[4];
    const float* Wm       = (const float*)d_in[5];
    const float* Wc       = (const float*)d_in[6];
    const float* v        = (const float*)d_in[7];

    char* ws = (char*)d_ws;
    short* Wt      = (short*)ws;                       // 512 KB
    float* h       = (float*)(ws + 512 * 1024);        // 64 KB
    float* mWS     = (float*)(ws + 576 * 1024);        // 4 KB (32 x 32)
    float* lWS     = (float*)(ws + 580 * 1024);        // 4 KB
    float* ctxPart = (float*)(ws + 584 * 1024);        // 2 MB (32 x 32 x 512)
    // total ws use: 2.57 MB  (<= 2.625 MB proven envelope)

    float* ctx  = (float*)d_out;
    float* attn = (float*)d_out + BB * 512;            // doubles as p buffer

    hipMemsetAsync(h, 0, BB * 512 * sizeof(float), stream);
    prep_wt_kernel<<<dim3(16, 16), dim3(256), 0, stream>>>(Wm, Wt);
    prep_h_kernel<<<dim3(32, 2, 4), dim3(256), 0, stream>>>(hidden, Wh, h);
    fused_kernel<<<dim3(BB * 32), dim3(1024), 0, stream>>>(
        memory, coverage, mem_pad, Wt, h, Wc, v, attn, mWS, lWS, ctxPart);
    combine_kernel<<<dim3(BB), dim3(512), 0, stream>>>(mWS, lWS, ctxPart, ctx, attn);
}